// Round 10
// baseline (69.851 us; speedup 1.0000x reference)
//
#include <hip/hip_runtime.h>
#include <hip/hip_bf16.h>
#include <math.h>

#define N_TOT   16384
#define M_EV    4096
#define IN_DIM  128
#define SPACE_D 4
#define PROP_D  64
#define K_NN    32
#define CAND_CAP 128            // survivor slots per row (2/lane)
#define M_SCALED 0.25f          // prune margin in scaled (8x) domain = 0.031 true

typedef _Float16 h2 __attribute__((ext_vector_type(2)));
typedef __attribute__((ext_vector_type(8))) _Float16 h16x8;
typedef __attribute__((ext_vector_type(4))) float f32x4;
typedef unsigned long long u64;

__device__ __forceinline__ h2 pkrtz(float a, float b) {
  return __builtin_bit_cast(h2, __builtin_amdgcn_cvt_pkrtz(a, b));
}
__device__ __forceinline__ unsigned fmap(float f) {   // monotone f32->u32
  unsigned b = __float_as_uint(f);
  return (b & 0x80000000u) ? ~b : (b | 0x80000000u);
}
__device__ __forceinline__ float funmap(unsigned u) {
  unsigned b = (u & 0x80000000u) ? (u & 0x7FFFFFFFu) : ~u;
  return __uint_as_float(b);
}
__device__ __forceinline__ int mbcnt64(u64 mk) {
  return (int)__builtin_amdgcn_mbcnt_hi((unsigned)(mk >> 32),
           __builtin_amdgcn_mbcnt_lo((unsigned)mk, 0u));
}

// ---------------------------------------------------------------------------
// Kernel 1: space = x @ Ws + bs ; prop = x @ Wp + bp   (unchanged, proven)
// ---------------------------------------------------------------------------
__global__ __launch_bounds__(256) void linear_kernel(
    const float* __restrict__ x,
    const float* __restrict__ Ws, const float* __restrict__ bs,
    const float* __restrict__ Wp, const float* __restrict__ bp,
    float* __restrict__ space, float* __restrict__ prop)
{
  const int lane = threadIdx.x & 63;
  const int wid  = threadIdx.x >> 6;
  const int r0   = __builtin_amdgcn_readfirstlane((int)blockIdx.x * 16 + wid * 4);

  const float* xr = x + (size_t)r0 * IN_DIM;

  float a0 = bp[lane];
  float a1 = a0, a2 = a0, a3 = a0;
  #pragma unroll
  for (int i = 0; i < IN_DIM; ++i) {
    const float w = Wp[i * PROP_D + lane];
    a0 = fmaf(xr[i],              w, a0);
    a1 = fmaf(xr[IN_DIM + i],     w, a1);
    a2 = fmaf(xr[2 * IN_DIM + i], w, a2);
    a3 = fmaf(xr[3 * IN_DIM + i], w, a3);
  }
  prop[(size_t)(r0 + 0) * PROP_D + lane] = a0;
  prop[(size_t)(r0 + 1) * PROP_D + lane] = a1;
  prop[(size_t)(r0 + 2) * PROP_D + lane] = a2;
  prop[(size_t)(r0 + 3) * PROP_D + lane] = a3;

  if (lane < 16) {
    const int r = lane >> 2, c = lane & 3;
    const float* xq = x + (size_t)(r0 + r) * IN_DIM;
    float a = bs[c];
    #pragma unroll
    for (int i = 0; i < IN_DIM; ++i)
      a = fmaf(xq[i], Ws[i * SPACE_D + c], a);
    space[(size_t)(r0 + r) * SPACE_D + c] = a;
  }
}

// ---------------------------------------------------------------------------
// Kernel 2: per-row exact KNN (K=32 of 4096) + weighted aggregation.
// 512 thr = 8 waves = 2 row-tiles(16 rows) x 4 cand-quarters; 32 rows/block.
// Distances via mfma_f32_16x16x32_f16: A = per-row [-2q] pattern replicated
// over all k-slots, B = per-cand coords replicated likewise -> frag = 8*(-2q.c)
// (k-group mapping cancels). val = frag + 8c^2 (staged f32). Pass A: running
// min per (row, col-slot) -> 64 partition mins/row -> Tub bisect (tail wave).
// Pass B: MFMA re-run + compare vs T[row] + LDS-atomic append of u16 indices.
// Tail (4 rows/wave): exact f32 refine from global, f32-bit bisect, stable
// lowest-index tie select (JAX semantics), weighted mean/max aggregation.
// Cold exact fallback if survivors > CAND_CAP.
// ---------------------------------------------------------------------------
__global__ __launch_bounds__(512, 4) void knn_kernel(
    const float4* __restrict__ space,   // [N_TOT] f32 coords
    const float*  __restrict__ prop,    // [N_TOT * PROP_D]
    float*        __restrict__ out)     // [N_TOT * 2*PROP_D]
{
  const int lane = threadIdx.x & 63;
  const int wid  = threadIdx.x >> 6;              // 0..7
  const int rt   = wid >> 2;                      // row-tile 0/1
  const int qq   = wid & 3;                       // candidate quarter
  const int brow0 = (int)blockIdx.x * 32;         // first global row of block
  const int m0    = brow0 & ~(M_EV - 1);          // event base
  const int ml0   = brow0 & (M_EV - 1);           // event-local first row

  __shared__ uint2          s_B[M_EV];            // 32 KB cand coords f16x4
  __shared__ float          s_c2[M_EV];           // 16 KB 8*c^2 (f32)
  __shared__ float          s_pmin[32][64];       // 8 KB partition mins
  __shared__ float          s_T[32];              // scaled threshold + margin
  __shared__ unsigned short s_ci[32][CAND_CAP];   // 8 KB survivor idx (u16)
  __shared__ int            s_cnt[32];
  __shared__ uint2          s_w[32][K_NN];        // 8 KB winners {idx,wbits}

  // --- stage: per-cand packed f16 coords + 8*c^2 ---
  {
    const float4* src = space + m0;
    #pragma unroll
    for (int it = 0; it < 8; ++it) {
      const int i = (int)threadIdx.x + it * 512;
      const float4 c = src[i];
      s_B[i] = make_uint2(
          __builtin_bit_cast(unsigned, pkrtz(c.x, c.y)),
          __builtin_bit_cast(unsigned, pkrtz(c.z, c.w)));
      s_c2[i] = 8.f * fmaf(c.x, c.x, fmaf(c.y, c.y, fmaf(c.z, c.z, c.w * c.w)));
    }
  }
  if (threadIdx.x < 32) s_cnt[threadIdx.x] = 0;
  __syncthreads();

  // --- A fragment: row = lane&15 of this wave's row-tile, pattern [-2q]x2 ---
  const float4 qa = space[m0 + ml0 + rt * 16 + (lane & 15)];
  const unsigned a01 = __builtin_bit_cast(unsigned, pkrtz(-2.f * qa.x, -2.f * qa.y));
  const unsigned a23 = __builtin_bit_cast(unsigned, pkrtz(-2.f * qa.z, -2.f * qa.w));
  uint4 au; au.x = a01; au.y = a23; au.z = a01; au.w = a23;
  const h16x8 afrag = __builtin_bit_cast(h16x8, au);

  const int cbase = qq * 1024;                    // this wave's cand quarter

  // --- pass A: running min per (row_j, col) slot over 64 tiles ---
  f32x4 mna = {INFINITY, INFINITY, INFINITY, INFINITY};
  #pragma unroll 8
  for (int t = 0; t < 64; ++t) {
    const int cb = cbase + t * 16;
    const uint2 b = s_B[cb + (lane & 15)];
    const float c2s = s_c2[cb + (lane & 15)];
    uint4 bu; bu.x = b.x; bu.y = b.y; bu.z = b.x; bu.w = b.y;
    const h16x8 bfrag = __builtin_bit_cast(h16x8, bu);
    f32x4 acc = {0.f, 0.f, 0.f, 0.f};
    acc = __builtin_amdgcn_mfma_f32_16x16x32_f16(afrag, bfrag, acc, 0, 0, 0);
    #pragma unroll
    for (int j = 0; j < 4; ++j) {
      const float v = acc[j] + c2s;               // 8*(c^2 - 2 q.c)
      mna[j] = fminf(mna[j], v);
    }
  }
  {
    const int r16 = (lane >> 4) * 4;              // C/D row group base
    #pragma unroll
    for (int j = 0; j < 4; ++j)
      s_pmin[rt * 16 + r16 + j][qq * 16 + (lane & 15)] = mna[j];
  }
  __syncthreads();

  // --- Tub per row: 32nd smallest of 64 partition mins (tail waves) ---
  #pragma unroll
  for (int rr = 0; rr < 4; ++rr) {
    const int br = wid * 4 + rr;                  // block-local row 0..31
    const unsigned u = fmap(s_pmin[br][lane]);
    unsigned lo = 0u, hi = 0xFFFFFFFFu;
    while (lo < hi) {
      const unsigned mid = lo + ((hi - lo) >> 1);
      const int c = (int)__popcll(__ballot(u <= mid));
      if (c >= K_NN) { hi = mid; if (c == K_NN) break; }
      else lo = mid + 1;
    }
    if (lane == 0) s_T[br] = funmap(hi) + M_SCALED;
  }
  __syncthreads();

  // --- pass B: MFMA re-run + compare + atomic append of survivor indices ---
  {
    const int r16 = (lane >> 4) * 4;
    int   rowj[4];
    float Tj[4];
    #pragma unroll
    for (int j = 0; j < 4; ++j) {
      rowj[j] = rt * 16 + r16 + j;
      Tj[j]   = s_T[rowj[j]];
    }
    #pragma unroll 8
    for (int t = 0; t < 64; ++t) {
      const int cb = cbase + t * 16;
      const uint2 b = s_B[cb + (lane & 15)];
      const float c2s = s_c2[cb + (lane & 15)];
      uint4 bu; bu.x = b.x; bu.y = b.y; bu.z = b.x; bu.w = b.y;
      const h16x8 bfrag = __builtin_bit_cast(h16x8, bu);
      f32x4 acc = {0.f, 0.f, 0.f, 0.f};
      acc = __builtin_amdgcn_mfma_f32_16x16x32_f16(afrag, bfrag, acc, 0, 0, 0);
      #pragma unroll
      for (int j = 0; j < 4; ++j) {
        const float v = acc[j] + c2s;
        if (v <= Tj[j]) {
          const int pos = atomicAdd(&s_cnt[rowj[j]], 1);
          s_ci[rowj[j]][pos & (CAND_CAP - 1)] =
              (unsigned short)(cb + (lane & 15));
        }
      }
    }
  }
  __syncthreads();

  // --- tail: 4 rows per wave: refine + exact select + aggregate ---
  const float* __restrict__ pb = prop + ((size_t)m0 << 6) + lane;
  #pragma unroll 1
  for (int rr = 0; rr < 4; ++rr) {
    const int br   = wid * 4 + rr;
    const int rloc = ml0 + br;
    const int grow = brow0 + br;
    int C = s_cnt[br];

    const float4 qf = space[m0 + rloc];           // wave-uniform
    const float q2f = fmaf(qf.x, qf.x, fmaf(qf.y, qf.y,
                      fmaf(qf.z, qf.z, qf.w * qf.w)));
    float Tt = s_T[br] * 0.125f + q2f;            // true-domain bound
    if (Tt < 0.f) Tt = 0.f;

    if (C > CAND_CAP) {
      // cold exact fallback: bisect exact f32 d^2 from global, fill top-32
      const float4* __restrict__ ev = space + m0;
      unsigned lo = 0u, hi = __float_as_uint(Tt);
      while (lo < hi) {
        const unsigned mid = lo + ((hi - lo) >> 1);
        const float fm = __uint_as_float(mid);
        int c = 0;
        #pragma unroll 1
        for (int t = 0; t < 64; ++t) {
          const float4 cc = ev[lane + (t << 6)];
          const float dx = qf.x - cc.x, dy = qf.y - cc.y;
          const float dz = qf.z - cc.z, dw = qf.w - cc.w;
          const float dd = fmaf(dx, dx, fmaf(dy, dy, fmaf(dz, dz, dw * dw)));
          c += (int)__popcll(__ballot(dd <= fm));
        }
        if (c >= K_NN) { hi = mid; if (c == K_NN) break; }
        else lo = mid + 1;
      }
      const float Tf = __uint_as_float(hi);
      int cnt = 0;
      #pragma unroll 1
      for (int pass = 0; pass < 2; ++pass) {      // 0: strict-less, 1: equal
        #pragma unroll 1
        for (int t = 0; t < 64; ++t) {
          const float4 cc = ev[lane + (t << 6)];
          const float dx = qf.x - cc.x, dy = qf.y - cc.y;
          const float dz = qf.z - cc.z, dw = qf.w - cc.w;
          const float dd = fmaf(dx, dx, fmaf(dy, dy, fmaf(dz, dz, dw * dw)));
          const bool p = pass ? (dd == Tf) : (dd < Tf);
          const u64 mk = __ballot(p);
          if (p) {
            const int pos = cnt + mbcnt64(mk);
            if (pos < K_NN) s_ci[br][pos] = (unsigned short)((t << 6) + lane);
          }
          cnt += (int)__popcll(mk);
        }
        if (cnt >= K_NN) break;
      }
      C = K_NN;
    }

    // refine: exact f32 distances for <=2 survivors/lane (global, L2-hot)
    const bool h0 = (lane < C), h1 = (64 + lane < C);
    const int i0 = h0 ? (int)s_ci[br][lane]      : 0;
    const int i1 = h1 ? (int)s_ci[br][64 + lane] : 0;
    float v0 = INFINITY, v1 = INFINITY;
    if (h0) {
      const float4 cc = space[m0 + i0];
      const float dx = qf.x - cc.x, dy = qf.y - cc.y;
      const float dz = qf.z - cc.z, dw = qf.w - cc.w;
      v0 = fmaf(dx, dx, fmaf(dy, dy, fmaf(dz, dz, dw * dw)));
    }
    if (h1) {
      const float4 cc = space[m0 + i1];
      const float dx = qf.x - cc.x, dy = qf.y - cc.y;
      const float dz = qf.z - cc.z, dw = qf.w - cc.w;
      v1 = fmaf(dx, dx, fmaf(dy, dy, fmaf(dz, dz, dw * dw)));
    }

    // f32-bits bisect (early exit) for the exact 32nd-smallest
    unsigned lo = 0u, hi = __float_as_uint(Tt);
    while (lo < hi) {
      const unsigned mid = lo + ((hi - lo) >> 1);
      const float fm = __uint_as_float(mid);
      const int c = (int)__popcll(__ballot(v0 <= fm)) +
                    (int)__popcll(__ballot(v1 <= fm));
      if (c >= K_NN) { hi = mid; if (c == K_NN) break; }
      else lo = mid + 1;
    }
    const float T2 = __uint_as_float(hi);

    // stable selection: strict-less, then lowest-position equals (JAX order)
    const u64 mkE0 = __ballot(v0 == T2);
    const u64 mkE1 = __ballot(v1 == T2);
    const int L = (int)__popcll(__ballot(v0 < T2)) +
                  (int)__popcll(__ballot(v1 < T2));
    const int e = K_NN - L;
    const int nE0 = (int)__popcll(mkE0);
    const bool sel0 = (v0 < T2) || ((v0 == T2) && (mbcnt64(mkE0) < e));
    const bool sel1 = (v1 < T2) || ((v1 == T2) && (nE0 + mbcnt64(mkE1) < e));

    const float w0 = __expf(-10.f * v0);
    const float w1 = __expf(-10.f * v1);
    {
      const u64 mkS0 = __ballot(sel0);
      if (sel0) {
        const int pos = mbcnt64(mkS0);
        s_w[br][pos] = make_uint2((unsigned)i0, __float_as_uint(w0));
      }
      const int b0 = (int)__popcll(mkS0);
      const u64 mkS1 = __ballot(sel1);
      if (sel1) {
        const int pos = b0 + mbcnt64(mkS1);
        s_w[br][pos] = make_uint2((unsigned)i1, __float_as_uint(w1));
      }
    }

    // aggregation: lane = feature, 32 winners
    float accm = 0.f;
    float accx = -INFINITY;
    #pragma unroll 8
    for (int n = 0; n < K_NN; ++n) {
      const uint2 wn = s_w[br][n];                // uniform LDS broadcast
      const float w = __uint_as_float(wn.y);
      const float v = pb[(size_t)wn.x << 6];      // coalesced 256B, L2-hot
      const float wv = w * v;
      accm += wv;
      accx = fmaxf(accx, wv);
    }
    out[(size_t)grow * 128 + lane]      = accm * (1.f / K_NN);
    out[(size_t)grow * 128 + 64 + lane] = accx;
  }
}

// ---------------------------------------------------------------------------
extern "C" void kernel_launch(void* const* d_in, const int* in_sizes, int n_in,
                              void* d_out, int out_size, void* d_ws, size_t ws_size,
                              hipStream_t stream) {
  const float* x  = (const float*)d_in[0];
  const float* Ws = (const float*)d_in[1];
  const float* bs = (const float*)d_in[2];
  const float* Wp = (const float*)d_in[3];
  const float* bp = (const float*)d_in[4];
  float* out = (float*)d_out;

  // workspace layout: prop [N,64] f32 (4 MB) | space [N,4] f32 (256 KB)
  float* prop  = (float*)d_ws;
  float* space = (float*)((char*)d_ws + (size_t)N_TOT * PROP_D * sizeof(float));

  linear_kernel<<<N_TOT / 16, 256, 0, stream>>>(x, Ws, bs, Wp, bp, space, prop);
  knn_kernel<<<N_TOT / 32, 512, 0, stream>>>((const float4*)space, prop, out);
}

// Round 11
// 53.368 us; speedup vs baseline: 1.3089x; 1.3089x over previous
//
#include <hip/hip_runtime.h>
#include <hip/hip_bf16.h>
#include <math.h>

#define N_TOT   16384
#define M_EV    4096
#define IN_DIM  128
#define SPACE_D 4
#define PROP_D  64
#define K_NN    32
#define CAND_CAP 128            // survivor slots per row (2/lane)
#define MARGIN  0.04f           // covers f16 approx error near threshold (>= 2*err)

typedef _Float16 h2 __attribute__((ext_vector_type(2)));
typedef unsigned long long u64;

__device__ __forceinline__ h2 pkmin(h2 a, h2 b) {
#if __has_builtin(__builtin_elementwise_min)
  return __builtin_elementwise_min(a, b);
#else
  h2 r; r.x = (a.x < b.x) ? a.x : b.x; r.y = (a.y < b.y) ? a.y : b.y; return r;
#endif
}

__device__ __forceinline__ h2 pkrtz(float a, float b) {
  return __builtin_bit_cast(h2, __builtin_amdgcn_cvt_pkrtz(a, b));
}

// ---------------------------------------------------------------------------
// Kernel 1: space = x @ Ws + bs ; prop = x @ Wp + bp
// float4 x loads (scalar dwordx4) to cut scalar-load issue count 4x.
// ---------------------------------------------------------------------------
__global__ __launch_bounds__(256) void linear_kernel(
    const float* __restrict__ x,
    const float* __restrict__ Ws, const float* __restrict__ bs,
    const float* __restrict__ Wp, const float* __restrict__ bp,
    float* __restrict__ space, float* __restrict__ prop)
{
  const int lane = threadIdx.x & 63;
  const int wid  = threadIdx.x >> 6;
  const int r0   = __builtin_amdgcn_readfirstlane((int)blockIdx.x * 16 + wid * 4);

  const float4* __restrict__ xr = (const float4*)(x + (size_t)r0 * IN_DIM);

  float a0 = bp[lane];
  float a1 = a0, a2 = a0, a3 = a0;
  #pragma unroll
  for (int i = 0; i < 32; ++i) {
    const float4 x0 = xr[i];
    const float4 x1 = xr[32 + i];
    const float4 x2 = xr[64 + i];
    const float4 x3 = xr[96 + i];
    #pragma unroll
    for (int d = 0; d < 4; ++d) {
      const float w = Wp[(i * 4 + d) * PROP_D + lane];
      a0 = fmaf(((const float*)&x0)[d], w, a0);
      a1 = fmaf(((const float*)&x1)[d], w, a1);
      a2 = fmaf(((const float*)&x2)[d], w, a2);
      a3 = fmaf(((const float*)&x3)[d], w, a3);
    }
  }
  prop[(size_t)(r0 + 0) * PROP_D + lane] = a0;
  prop[(size_t)(r0 + 1) * PROP_D + lane] = a1;
  prop[(size_t)(r0 + 2) * PROP_D + lane] = a2;
  prop[(size_t)(r0 + 3) * PROP_D + lane] = a3;

  if (lane < 16) {
    const int r = lane >> 2, c = lane & 3;
    const float4* __restrict__ xq = (const float4*)(x + (size_t)(r0 + r) * IN_DIM);
    float a = bs[c];
    #pragma unroll
    for (int i = 0; i < 32; ++i) {
      const float4 v = xq[i];
      a = fmaf(v.x, Ws[(i * 4 + 0) * SPACE_D + c], a);
      a = fmaf(v.y, Ws[(i * 4 + 1) * SPACE_D + c], a);
      a = fmaf(v.z, Ws[(i * 4 + 2) * SPACE_D + c], a);
      a = fmaf(v.w, Ws[(i * 4 + 3) * SPACE_D + c], a);
    }
    space[(size_t)(r0 + r) * SPACE_D + c] = a;
  }
}

// per-lane count of set bits of mk strictly below this lane
__device__ __forceinline__ int mbcnt64(u64 mk) {
  return (int)__builtin_amdgcn_mbcnt_hi((unsigned)(mk >> 32),
           __builtin_amdgcn_mbcnt_lo((unsigned)mk, 0u));
}

// ---------------------------------------------------------------------------
// Kernel 2: per-row exact KNN (K=32 of 4096) + weighted aggregation.
// 512 threads = 8 waves = 8 rows. Slab pair-packed f16 in LDS (32 KB).
// Pass A: all 4096 approx distances once -> 32 packed h2 VGPRs + packed
// lane-min. An asm memory clobber between the passes makes remat-from-LDS
// illegal, so pass B is truly register-only (launch_bounds(512,6) gives the
// VGPR budget). Tub: 15-iter integer bisect on f16 CODE space of the 128
// partition mins. Pass B: f16 compares + LDS-atomic append of indices.
// Refine: exact f32 from global for <=2 survivors/lane. Tail: f32-bits bisect
// (early exit) + stable lowest-index tie select (exact = JAX semantics).
// Cold exact fallback if survivors > 128.
// ---------------------------------------------------------------------------
__global__ __launch_bounds__(512, 6) void knn_kernel(
    const float4* __restrict__ space,   // [N_TOT] f32 coords
    const float*  __restrict__ prop,    // [N_TOT * PROP_D]
    float*        __restrict__ out)     // [N_TOT * 2*PROP_D]
{
  const int lane = threadIdx.x & 63;
  const int wid  = threadIdx.x >> 6;              // 0..7
  const int row  = (int)blockIdx.x * 8 + wid;     // 1 wave = 1 row
  const int m0   = row & ~(M_EV - 1);
  const int mloc = row & (M_EV - 1);

  __shared__ uint4 s_pk[M_EV / 2];                // 32 KB pair-packed f16
  __shared__ int   s_ci[8][CAND_CAP];             // 4 KB survivor indices
  __shared__ uint2 s_w[8][K_NN];                  // 2 KB winners {idx, wbits}
  __shared__ int   s_cnt[8];

  // stage: pack pairs (i, i+2048) as f16x2 per dim
  {
    const float4* src = space + m0;
    #pragma unroll
    for (int it = 0; it < 4; ++it) {
      const int i = (int)threadIdx.x + it * 512;
      const float4 a = src[i];
      const float4 b = src[i + 2048];
      s_pk[i] = make_uint4(
        __builtin_bit_cast(unsigned, pkrtz(a.x, b.x)),
        __builtin_bit_cast(unsigned, pkrtz(a.y, b.y)),
        __builtin_bit_cast(unsigned, pkrtz(a.z, b.z)),
        __builtin_bit_cast(unsigned, pkrtz(a.w, b.w)));
    }
  }
  if (lane == 0) s_cnt[wid] = 0;
  __syncthreads();

  // query coords: exact f32 (for refine) + duplicated f16 packs
  const float4 qf = space[m0 + mloc];
  const h2 qx = pkrtz(qf.x, qf.x), qy = pkrtz(qf.y, qf.y);
  const h2 qz = pkrtz(qf.z, qf.z), qw = pkrtz(qf.w, qf.w);

  // --- pass A: packed distances -> 32 registers + running packed min ---
  unsigned pd[32];
  h2 mn; mn.x = (_Float16)65504.f; mn.y = (_Float16)65504.f;
  #pragma unroll
  for (int t = 0; t < 32; ++t) {
    const uint4 u = s_pk[lane + (t << 6)];
    const h2 dx = qx - __builtin_bit_cast(h2, u.x);
    const h2 dy = qy - __builtin_bit_cast(h2, u.y);
    const h2 dz = qz - __builtin_bit_cast(h2, u.z);
    const h2 dw = qw - __builtin_bit_cast(h2, u.w);
    h2 s = dx * dx;
    s = dy * dy + s;
    s = dz * dz + s;
    s = dw * dw + s;
    pd[t] = __builtin_bit_cast(unsigned, s);
    mn = pkmin(mn, s);
  }

  // --- Tub: 32nd smallest of 128 partition mins, bisect on f16 CODE space ---
  const unsigned mnbits = __builtin_bit_cast(unsigned, mn);
  const unsigned c0 = mnbits & 0xFFFFu, c1 = mnbits >> 16;
  unsigned blo = 0u, bhi = 0x7C00u;
  while (blo < bhi) {
    const unsigned mid = (blo + bhi) >> 1;
    const int c = (int)__popcll(__ballot(c0 <= mid)) +
                  (int)__popcll(__ballot(c1 <= mid));
    if (c >= K_NN) { bhi = mid; if (c == K_NN) break; }
    else blo = mid + 1;
  }
  const float T = (float)__builtin_bit_cast(_Float16, (unsigned short)bhi) + MARGIN;
  const h2 Th = pkrtz(T, T);                      // RTZ error << MARGIN

  // memory clobber: re-reading s_pk after this is illegal -> pd must stay
  // in registers (or spill, which WRITE_SIZE would expose). Kills the remat.
  asm volatile("" ::: "memory");

  // --- pass B: register-only compares + LDS-atomic append of indices ---
  #pragma unroll
  for (int t = 0; t < 32; ++t) {
    const h2 s = __builtin_bit_cast(h2, pd[t]);
    if (s.x <= Th.x) {
      const int pos = atomicAdd(&s_cnt[wid], 1);
      if (pos < CAND_CAP) s_ci[wid][pos] = (t << 6) + lane;
    }
    if (s.y <= Th.y) {
      const int pos = atomicAdd(&s_cnt[wid], 1);
      if (pos < CAND_CAP) s_ci[wid][pos] = (t << 6) + lane + 2048;
    }
  }
  int C = s_cnt[wid];

  if (C > CAND_CAP) {
    // --- cold exact fallback: bisect exact f32 d from global, fill top-32 ---
    const float4* __restrict__ ev = space + m0;
    unsigned lo = 0u, hi = __float_as_uint(T);
    while (lo < hi) {
      const unsigned mid = (lo + hi) >> 1;
      const float fm = __uint_as_float(mid);
      int c = 0;
      #pragma unroll 1
      for (int t = 0; t < 64; ++t) {
        const float4 cc = ev[lane + (t << 6)];
        const float dx = qf.x - cc.x, dy = qf.y - cc.y;
        const float dz = qf.z - cc.z, dw = qf.w - cc.w;
        const float dd = fmaf(dx, dx, fmaf(dy, dy, fmaf(dz, dz, dw * dw)));
        c += (int)__popcll(__ballot(dd <= fm));
      }
      if (c >= K_NN) { hi = mid; if (c == K_NN) break; }
      else lo = mid + 1;
    }
    const float Tf = __uint_as_float(hi);
    int cnt = 0;
    #pragma unroll 1
    for (int pass = 0; pass < 2; ++pass) {        // 0: strict-less, 1: equal
      #pragma unroll 1
      for (int t = 0; t < 64; ++t) {
        const float4 cc = ev[lane + (t << 6)];
        const float dx = qf.x - cc.x, dy = qf.y - cc.y;
        const float dz = qf.z - cc.z, dw = qf.w - cc.w;
        const float dd = fmaf(dx, dx, fmaf(dy, dy, fmaf(dz, dz, dw * dw)));
        const bool p = pass ? (dd == Tf) : (dd < Tf);
        const u64 mk = __ballot(p);
        if (p) {
          const int pos = cnt + mbcnt64(mk);
          if (pos < K_NN) s_ci[wid][pos] = (t << 6) + lane;
        }
        cnt += (int)__popcll(mk);
      }
      if (cnt >= K_NN) break;
    }
    C = K_NN;
  }

  // --- refine: exact f32 distances for <=2 survivors/lane (global, L2) ---
  const bool h0 = (lane < C), h1 = (64 + lane < C);
  const int i0 = h0 ? s_ci[wid][lane]      : 0;
  const int i1 = h1 ? s_ci[wid][64 + lane] : 0;
  float v0 = INFINITY, v1 = INFINITY;
  if (h0) {
    const float4 cc = space[m0 + i0];
    const float dx = qf.x - cc.x, dy = qf.y - cc.y;
    const float dz = qf.z - cc.z, dw = qf.w - cc.w;
    v0 = fmaf(dx, dx, fmaf(dy, dy, fmaf(dz, dz, dw * dw)));
  }
  if (h1) {
    const float4 cc = space[m0 + i1];
    const float dx = qf.x - cc.x, dy = qf.y - cc.y;
    const float dz = qf.z - cc.z, dw = qf.w - cc.w;
    v1 = fmaf(dx, dx, fmaf(dy, dy, fmaf(dz, dz, dw * dw)));
  }

  // --- tail: f32-bits bisect (early exit at c==32) on <=2 values/lane ---
  unsigned lo = 0u, hi = __float_as_uint(T);
  while (lo < hi) {
    const unsigned mid = (lo + hi) >> 1;
    const float fm = __uint_as_float(mid);
    const int c = (int)__popcll(__ballot(v0 <= fm)) +
                  (int)__popcll(__ballot(v1 <= fm));
    if (c >= K_NN) { hi = mid; if (c == K_NN) break; }
    else lo = mid + 1;
  }
  const float T2 = __uint_as_float(hi);

  // stable selection: strict-less, then lowest-position equals (JAX order)
  const u64 mkE0 = __ballot(v0 == T2);
  const u64 mkE1 = __ballot(v1 == T2);
  const int L = (int)__popcll(__ballot(v0 < T2)) +
                (int)__popcll(__ballot(v1 < T2));
  const int e = K_NN - L;
  const int nE0 = (int)__popcll(mkE0);
  const bool sel0 = (v0 < T2) || ((v0 == T2) && (mbcnt64(mkE0) < e));
  const bool sel1 = (v1 < T2) || ((v1 == T2) && (nE0 + mbcnt64(mkE1) < e));

  const float w0 = __expf(-10.f * v0);
  const float w1 = __expf(-10.f * v1);

  {
    const u64 mkS0 = __ballot(sel0);
    if (sel0) {
      const int pos = mbcnt64(mkS0);
      s_w[wid][pos] = make_uint2((unsigned)i0, __float_as_uint(w0));
    }
    const int b0 = (int)__popcll(mkS0);
    const u64 mkS1 = __ballot(sel1);
    if (sel1) {
      const int pos = b0 + mbcnt64(mkS1);
      s_w[wid][pos] = make_uint2((unsigned)i1, __float_as_uint(w1));
    }
  }

  // --- aggregation: lane = feature, 32 winners ---
  float accm = 0.f;
  float accx = -INFINITY;
  const float* __restrict__ pb = prop + ((size_t)m0 << 6) + lane;
  #pragma unroll 8
  for (int n = 0; n < K_NN; ++n) {
    const uint2 wn = s_w[wid][n];                 // uniform LDS broadcast
    const float w = __uint_as_float(wn.y);
    const float v = pb[(size_t)wn.x << 6];        // coalesced 256B, L2-hot
    const float wv = w * v;
    accm += wv;
    accx = fmaxf(accx, wv);
  }
  out[(size_t)row * 128 + lane]      = accm * (1.f / K_NN);
  out[(size_t)row * 128 + 64 + lane] = accx;
}

// ---------------------------------------------------------------------------
extern "C" void kernel_launch(void* const* d_in, const int* in_sizes, int n_in,
                              void* d_out, int out_size, void* d_ws, size_t ws_size,
                              hipStream_t stream) {
  const float* x  = (const float*)d_in[0];
  const float* Ws = (const float*)d_in[1];
  const float* bs = (const float*)d_in[2];
  const float* Wp = (const float*)d_in[3];
  const float* bp = (const float*)d_in[4];
  float* out = (float*)d_out;

  // workspace layout: prop [N,64] f32 (4 MB) | space [N,4] f32 (256 KB)
  float* prop  = (float*)d_ws;
  float* space = (float*)((char*)d_ws + (size_t)N_TOT * PROP_D * sizeof(float));

  linear_kernel<<<N_TOT / 16, 256, 0, stream>>>(x, Ws, bs, Wp, bp, space, prop);
  knn_kernel<<<N_TOT / 8, 512, 0, stream>>>((const float4*)space, prop, out);
}